// Round 8
// baseline (705.980 us; speedup 1.0000x reference)
//
#include <hip/hip_runtime.h>
#include <cstddef>
#include <cstdint>

// Shapes fixed by reference setup_inputs():
#define T_LEN 2048
#define B_SZ  32
#define D_SZ  512
#define BD    (B_SZ * D_SZ)   // 16384

// ---------------------------------------------------------------------------
// GEMM: per output element, single sequential fmaf chain over k=0..511
// ascending, then + bias[e]. Chain order (k0 asc, kq asc, x/y/z/w asc)
// bit-exact vs ref.
//
// R8 = R5's proven compute body (464-470 us, VGPR 80, twice measured;
// R7's "read-once" named-A variant regressed to 516 — do not restore it)
// + counted-vmcnt 3-buffer pipeline (T4, m218):
//  - LDS buffers x3 (48 KB): body(c) stages chunk c+2 into buf[(c+2)%3],
//    computes buf[c%3], then `s_waitcnt vmcnt(4)` + raw s_barrier — the
//    just-issued 4 glds stay IN FLIGHT across the barrier (vmcnt retires
//    in issue order, so waiting to depth 4 proves the previous body's
//    stage landed). No vmcnt(0) drain in the main loop.
//  - Buffer safety: one barrier per body keeps waves within one body;
//    buf[(c+2)%3] was last read in body c-1, behind a barrier.
//  - glds staging (no ds_write, no prefetch regs), XOR quad swizzles on
//    A (p=q^(row&3)) and B (p=q^((row>>1)&3)) with inverse-swizzled global
//    source (rule #21), bijective XCD swizzle (FETCH 272->85 MB proven).
// NOTE: SQ_LDS_BANK_CONFLICT ~3.3e7 is a glds wide-write artifact, not a
// real read conflict. NOTE: plain __launch_bounds__(256); (256,4) spilled
// acc (8.5x regression). Do not re-add.
// ---------------------------------------------------------------------------
#define BM   128
#define BN   128

typedef const __attribute__((address_space(1))) uint32_t* gas1_t;
typedef __attribute__((address_space(3))) uint32_t* las3_t;

__global__ __launch_bounds__(256) void gemm8x8_kernel(
    const float* __restrict__ A,     // [rows, 512]
    const float* __restrict__ W,     // [512, 512]
    const float* __restrict__ bias,  // [512]
    float* __restrict__ Y)           // [rows, 512]
{
#pragma clang fp contract(off)
  __shared__ float As[3][BM * 16];     // 8 KB per buf, linear, glds dest
  __shared__ float Bs[3][BN * 16];     // 8 KB per buf, linear, glds dest

  const int tid = threadIdx.x;
  const int tx  = tid & 15;          // n-lane: n = tx + 16*j
  const int ty  = tid >> 4;          // m-lane: m = ty + 16*i (0..15)
  const int cA  = ty & 3;            // A read-side quad XOR
  const int cB  = (tx >> 1) & 3;     // B read-side quad XOR

  // Bijective XCD swizzle (n-fast).
  const int nwg  = (int)(gridDim.x * gridDim.y);
  const int orig = (int)(blockIdx.y * gridDim.x + blockIdx.x);
  const int q    = nwg >> 3, r = nwg & 7;
  const int xcd  = orig & 7, loc = orig >> 3;
  const int tix  = (xcd < r ? xcd * (q + 1) : r * (q + 1) + (xcd - r) * q) + loc;
  const int m0   = (tix >> 2) * BM;   // gridDim.y == 4 (D_SZ/BN)
  const int n0   = (tix & 3) * BN;

  // glds staging: wave w stages A segs {2w,2w+1} and B segs {2w,2w+1};
  // lane l lands at seg_base + l*16B. Lane fetches the logical quad that
  // belongs at its phys slot: A: (l&3)^(rloc&3); B: (l&3)^((rloc>>1)&3).
  const int lane  = tid & 63;
  const int wid   = tid >> 6;                      // 0..3
  const int rloc  = lane >> 2;
  const int qA4   = (((lane & 3) ^ (rloc & 3)) << 2);
  const int qB4   = (((lane & 3) ^ ((rloc >> 1) & 3)) << 2);
  const int s0    = 2 * wid, s1 = 2 * wid + 1;
  const int oS0   = s0 * 256, oS1 = s1 * 256;      // LDS float offsets
  const float* gA0 = A + (size_t)(m0 + s0 * 16 + rloc) * D_SZ + qA4;
  const float* gA1 = A + (size_t)(m0 + s1 * 16 + rloc) * D_SZ + qA4;
  const float* gB0 = W + (size_t)(n0 + s0 * 16 + rloc) * D_SZ + qB4;
  const float* gB1 = W + (size_t)(n0 + s1 * 16 + rloc) * D_SZ + qB4;

#define STAGE(BUF, KOFF)                                                      \
  do {                                                                        \
    __builtin_amdgcn_global_load_lds((gas1_t)(const void*)(gA0 + (KOFF)),     \
                                     (las3_t)(void*)(&As[BUF][oS0]), 16, 0, 0);\
    __builtin_amdgcn_global_load_lds((gas1_t)(const void*)(gA1 + (KOFF)),     \
                                     (las3_t)(void*)(&As[BUF][oS1]), 16, 0, 0);\
    __builtin_amdgcn_global_load_lds((gas1_t)(const void*)(gB0 + (KOFF)),     \
                                     (las3_t)(void*)(&Bs[BUF][oS0]), 16, 0, 0);\
    __builtin_amdgcn_global_load_lds((gas1_t)(const void*)(gB1 + (KOFF)),     \
                                     (las3_t)(void*)(&Bs[BUF][oS1]), 16, 0, 0);\
  } while (0)

  // R5's proven compute body, unchanged.
#define COMP(BUF)                                                             \
  {                                                                           \
    const float* asb = &As[BUF][0];                                           \
    const float* bsb = &Bs[BUF][0];                                           \
    _Pragma("unroll")                                                         \
    for (int kq = 0; kq < 4; ++kq) {                                          \
      const int bq = ((kq ^ cB) & 3) << 2;                                    \
      const int aq = ((kq ^ cA) & 3) << 2;                                    \
      float4 bfr[8];                                                          \
      _Pragma("unroll")                                                       \
      for (int j = 0; j < 8; ++j)                                             \
        bfr[j] = *(const float4*)&bsb[(tx + 16 * j) * 16 + bq];               \
      _Pragma("unroll")                                                       \
      for (int i = 0; i < 8; ++i) {                                           \
        const float4 a = *(const float4*)&asb[(ty + 16 * i) * 16 + aq];       \
        _Pragma("unroll")                                                     \
        for (int j = 0; j < 8; ++j) {                                         \
          acc[i][j] = fmaf(a.x, bfr[j].x, acc[i][j]);                         \
          acc[i][j] = fmaf(a.y, bfr[j].y, acc[i][j]);                         \
          acc[i][j] = fmaf(a.z, bfr[j].z, acc[i][j]);                         \
          acc[i][j] = fmaf(a.w, bfr[j].w, acc[i][j]);                         \
        }                                                                     \
      }                                                                       \
    }                                                                         \
  }

  // Counted wait + barrier: previous body's 4 glds retired; this body's
  // 4 stay in flight. "memory" clobber orders LDS reads across it.
#define SYNC_CNT4                                                             \
  do {                                                                        \
    asm volatile("s_waitcnt vmcnt(4)" ::: "memory");                          \
    __builtin_amdgcn_s_barrier();                                             \
    asm volatile("" ::: "memory");                                            \
  } while (0)

#define BODY(CBUF, SBUF, KOFF)                                                \
  do { STAGE(SBUF, KOFF); COMP(CBUF); SYNC_CNT4; } while (0)

  float acc[8][8];
#pragma unroll
  for (int i = 0; i < 8; ++i)
#pragma unroll
    for (int j = 0; j < 8; ++j) acc[i][j] = 0.0f;

  // Prologue: chunks 0,1 staged; wait depth 4 -> chunk 0 landed.
  STAGE(0, 0);
  STAGE(1, 16);
  SYNC_CNT4;

  // Main loop: 10 iters x 3 bodies = chunks 0..29; stages chunks 2..31.
#pragma unroll 1
  for (int t = 0; t < 10; ++t) {
    const int kc = 3 * t;
    BODY(0, 2, (kc + 2) * 16);
    BODY(1, 0, (kc + 3) * 16);
    BODY(2, 1, (kc + 4) * 16);
  }

  // Epilogue: chunk 30 (landed by last SYNC_CNT4), then drain for chunk 31.
  COMP(0);
  asm volatile("s_waitcnt vmcnt(0)" ::: "memory");
  __builtin_amdgcn_s_barrier();
  asm volatile("" ::: "memory");
  COMP(1);

#undef BODY
#undef SYNC_CNT4
#undef COMP
#undef STAGE

#pragma unroll
  for (int i = 0; i < 8; ++i) {
    const int m = m0 + ty + 16 * i;
#pragma unroll
    for (int j = 0; j < 8; ++j) {
      const int n = n0 + tx + 16 * j;
      Y[(size_t)m * D_SZ + n] = acc[i][j] + bias[n];
    }
  }
}

// ---------------------------------------------------------------------------
// Chunked LIF scan with warm-up (R7 version, measured ~160 us — UNCHANGED).
// T split into CHK=16 chunks of CLEN=128; 64-step warm-up per direction
// (bit-exact: 2^-64 residual + hard reset to exact 0; absmax=0 in R5/R6/R7).
// ca/cb ping-pong hides load latency under the dependent 384-cyc chain.
// ---------------------------------------------------------------------------
#define CHK  16
#define CLEN 128

__global__ __launch_bounds__(64) void scan_chunk_kernel(
    const float* __restrict__ Y,
    float* __restrict__ out)
{
#pragma clang fp contract(off)
  const int idx = blockIdx.x * 64 + threadIdx.x;   // column in [0, BD)
  const int c   = blockIdx.y;                      // chunk
  const int t0  = c * CLEN;
  float ca[32], cb[32];
  uint32_t sf0, sf1, sf2, sf3, sb0, sb1, sb2, sb3;
  float v;

#define LD(R, TB)                                                             \
  _Pragma("unroll")                                                           \
  for (int j = 0; j < 32; ++j) R[j] = Y[(size_t)((TB) + j) * BD + idx];

#define FCH(R, W)                                                             \
  {                                                                           \
    uint32_t w_ = 0;                                                          \
    _Pragma("unroll")                                                         \
    for (int j = 0; j < 32; ++j) {                                            \
      v = v + (R[j] - v) * 0.5f;                                              \
      const bool s = (v - 1.0f) >= 0.0f;                                      \
      w_ |= (uint32_t)s << j;                                                 \
      v = s ? 0.0f : v;                                                       \
    }                                                                         \
    W = w_;                                                                   \
  }

#define BCH(R, W)                                                             \
  {                                                                           \
    uint32_t w_ = 0;                                                          \
    _Pragma("unroll")                                                         \
    for (int j = 31; j >= 0; --j) {                                           \
      v = v + (R[j] - v) * 0.5f;                                              \
      const bool s = (v - 1.0f) >= 0.0f;                                      \
      w_ |= (uint32_t)s << j;                                                 \
      v = s ? 0.0f : v;                                                       \
    }                                                                         \
    W = w_;                                                                   \
  }

  uint32_t wdump;   // warm-up bit sink (dead)

  // ---------------- forward (t ascending) ----------------
  v = 0.0f;
  if (c > 0) {                       // warm-up: 64 steps over tail of prev
    LD(ca, t0 - 64)
    LD(cb, t0 - 32)
    FCH(ca, wdump)
    LD(ca, t0)                       // real group 0 loads fly under cb chain
    FCH(cb, wdump)
  } else {
    LD(ca, t0)
  }
  LD(cb, t0 + 32)  FCH(ca, sf0)
  LD(ca, t0 + 64)  FCH(cb, sf1)
  LD(cb, t0 + 96)  FCH(ca, sf2)
                   FCH(cb, sf3)

  // ---------------- backward (t descending) ----------------
  v = 0.0f;
  if (c < CHK - 1) {                 // warm-up: 64 steps over head of next
    LD(ca, t0 + CLEN + 32)
    LD(cb, t0 + CLEN)
    BCH(ca, wdump)
    LD(ca, t0 + 96)                  // real group 3 loads fly under cb chain
    BCH(cb, wdump)
  } else {
    LD(ca, t0 + 96)
  }
  LD(cb, t0 + 64)  BCH(ca, sb3)
  LD(ca, t0 + 32)  BCH(cb, sb2)
  LD(cb, t0)       BCH(ca, sb1)
                   BCH(cb, sb0)

  // ---------------- write ----------------
#define WGRP(SF, SB, G)                                                       \
  _Pragma("unroll")                                                           \
  for (int j = 0; j < 32; ++j)                                                \
    out[(size_t)(t0 + (G) * 32 + j) * BD + idx] =                             \
        (float)(((SF >> j) & 1u) + ((SB >> j) & 1u));
  WGRP(sf0, sb0, 0) WGRP(sf1, sb1, 1) WGRP(sf2, sb2, 2) WGRP(sf3, sb3, 3)

#undef LD
#undef FCH
#undef BCH
#undef WGRP
}

// ---------------------------------------------------------------------------
// Fallback scans (used only if ws is too small for full Y).
// ---------------------------------------------------------------------------
__global__ __launch_bounds__(64) void lif_fwd_kernel(
    const float* __restrict__ Y, float* __restrict__ out,
    int tlen, float* __restrict__ vstate, int carry)
{
#pragma clang fp contract(off)
  const int idx = blockIdx.x * 64 + threadIdx.x;
  float v = carry ? vstate[idx] : 0.0f;
#pragma unroll 16
  for (int t = 0; t < tlen; ++t) {
    const float c = Y[(size_t)t * BD + idx];
    v = v + (c - v) * 0.5f;
    const bool s = (v - 1.0f) >= 0.0f;
    out[(size_t)t * BD + idx] = s ? 1.0f : 0.0f;
    v = s ? 0.0f : v;
  }
  vstate[idx] = v;
}

__global__ __launch_bounds__(64) void lif_bwd_kernel(
    const float* __restrict__ Y, float* __restrict__ out,
    int tlen, float* __restrict__ vstate, int carry)
{
#pragma clang fp contract(off)
  const int idx = blockIdx.x * 64 + threadIdx.x;
  float v = carry ? vstate[idx] : 0.0f;
#pragma unroll 16
  for (int tt = 0; tt < tlen; ++tt) {
    const size_t t = (size_t)(tlen - 1 - tt);
    const float c = Y[t * BD + idx];
    v = v + (c - v) * 0.5f;
    const bool s = (v - 1.0f) >= 0.0f;
    out[t * BD + idx] += s ? 1.0f : 0.0f;
    v = s ? 0.0f : v;
  }
  vstate[idx] = v;
}

// ---------------------------------------------------------------------------
extern "C" void kernel_launch(void* const* d_in, const int* in_sizes, int n_in,
                              void* d_out, int out_size, void* d_ws, size_t ws_size,
                              hipStream_t stream)
{
  const float* x = (const float*)d_in[0];   // [T, B, D]
  const float* W = (const float*)d_in[1];   // [D, D]
  const float* b = (const float*)d_in[2];   // [D]
  float* out = (float*)d_out;               // [T, B, D]

  const size_t full_bytes = (size_t)T_LEN * BD * sizeof(float);     // 134 MB
  const size_t vbytes     = (size_t)BD * sizeof(float);

  if (ws_size >= full_bytes) {
    float* Y = (float*)d_ws;
    dim3 grid(T_LEN * B_SZ / BM, D_SZ / BN);
    gemm8x8_kernel<<<grid, 256, 0, stream>>>(x, W, b, Y);
    scan_chunk_kernel<<<dim3(BD / 64, CHK), 64, 0, stream>>>(Y, out);
  } else {
    // Chunked fallback; Tc a power-of-two divisor of T_LEN (>=4) so chunk
    // rows are a multiple of BM=128.
    const size_t avail = ws_size > vbytes ? ws_size - vbytes : 0;
    int Tc = T_LEN;
    while (Tc > 4 && (size_t)Tc * BD * sizeof(float) > avail) Tc >>= 1;
    float* Y      = (float*)d_ws;
    float* vstate = (float*)((char*)d_ws + (size_t)Tc * BD * sizeof(float));

    int first = 1;
    for (int t0 = 0; t0 < T_LEN; t0 += Tc) {
      dim3 grid(Tc * B_SZ / BM, D_SZ / BN);
      gemm8x8_kernel<<<grid, 256, 0, stream>>>(x + (size_t)t0 * BD, W, b, Y);
      lif_fwd_kernel<<<BD / 64, 64, 0, stream>>>(Y, out + (size_t)t0 * BD, Tc,
                                                 vstate, first ? 0 : 1);
      first = 0;
    }
    first = 1;
    for (int t0 = T_LEN - Tc; t0 >= 0; t0 -= Tc) {
      dim3 grid(Tc * B_SZ / BM, D_SZ / BN);
      gemm8x8_kernel<<<grid, 256, 0, stream>>>(x + (size_t)t0 * BD, W, b, Y);
      lif_bwd_kernel<<<BD / 64, 64, 0, stream>>>(Y, out + (size_t)t0 * BD, Tc,
                                                 vstate, first ? 0 : 1);
      first = 0;
    }
  }
}